// Round 2
// baseline (2619.774 us; speedup 1.0000x reference)
//
#include <hip/hip_runtime.h>
#include <math.h>

typedef __bf16 bf16_t;
typedef __attribute__((ext_vector_type(8))) __bf16 bf16x8;
typedef __attribute__((ext_vector_type(4))) float f32x4;

#define D_MODEL   2048
#define L_SEQ     2048
#define BATCH     2
#define NTOK      4096      // BATCH * L_SEQ
#define N_HEADS   32
#define D_STATE   64
#define HEADDIM   64
#define D_INNER   2048
#define CONV_DIM  6144      // d_inner + 2*H*N
#define D_IN_PROJ 8224      // 2*d_inner + 2*H*N + H
#define INTER     5504

// ---------------------------------------------------------------------------
// async global->LDS (width 16B). HW dest = wave-uniform base + lane*16; our
// LDS layout is flat tid*16 so per-lane pointers match HW placement exactly.
__device__ __forceinline__ void gld_lds16(const void* g, void* l) {
    __builtin_amdgcn_global_load_lds(
        (const __attribute__((address_space(1))) unsigned int*)g,
        (__attribute__((address_space(3))) unsigned int*)l, 16, 0, 0);
}

// ---------------------------------------------------------------------------
// f32 -> bf16 convert, 8 elems/thread
__global__ __launch_bounds__(256) void cvt_kernel(
    const float* __restrict__ s, bf16_t* __restrict__ d, int n8)
{
    int i = blockIdx.x * 256 + threadIdx.x;
    if (i >= n8) return;
    const float4* s4 = (const float4*)s;
    float4 a = s4[2 * i], b = s4[2 * i + 1];
    bf16x8 r;
    r[0] = (bf16_t)a.x; r[1] = (bf16_t)a.y; r[2] = (bf16_t)a.z; r[3] = (bf16_t)a.w;
    r[4] = (bf16_t)b.x; r[5] = (bf16_t)b.y; r[6] = (bf16_t)b.z; r[7] = (bf16_t)b.w;
    ((bf16x8*)d)[i] = r;
}

// ---------------------------------------------------------------------------
// RMSNorm: one block per token row; f32 in, bf16 out.
__global__ __launch_bounds__(256) void rmsnorm_kernel(
    const float* __restrict__ x, const float* __restrict__ w,
    const float* __restrict__ mask, bf16_t* __restrict__ out)
{
    __shared__ float red[4];
    __shared__ float sinv;
    int row = blockIdx.x;
    const float* xr = x + (size_t)row * D_MODEL;
    float xv[8];
    float ss = 0.f;
#pragma unroll
    for (int i = 0; i < 8; ++i) {
        float v = xr[threadIdx.x + 256 * i];
        xv[i] = v;
        ss += v * v;
    }
    for (int off = 32; off >= 1; off >>= 1) ss += __shfl_down(ss, off, 64);
    int lane = threadIdx.x & 63, wv = threadIdx.x >> 6;
    if (lane == 0) red[wv] = ss;
    __syncthreads();
    if (threadIdx.x == 0) {
        float t = red[0] + red[1] + red[2] + red[3];
        sinv = rsqrtf(t / (float)D_MODEL + 1e-6f);
    }
    __syncthreads();
    float s = sinv;
    float m = mask ? mask[row] : 1.f;
    bf16_t* orow = out + (size_t)row * D_MODEL;
#pragma unroll
    for (int i = 0; i < 8; ++i) {
        int c = threadIdx.x + 256 * i;
        orow[c] = (bf16_t)(xv[i] * s * w[c] * m);
    }
}

// ---------------------------------------------------------------------------
// GEMM: O[M,N] = X[M,K] @ W[N,K]^T (+ optional f32 residual R), bf16 inputs,
// fp32 accum, OT output. 128x128 tile, BK=32, 4 waves 2x2, m97 structure.
template <bool RES, typename OT>
__global__ __launch_bounds__(256) void gemm_bt(
    const bf16_t* __restrict__ X, const bf16_t* __restrict__ W,
    const float* __restrict__ R, OT* __restrict__ O,
    int N, int K)
{
    __shared__ __attribute__((aligned(16))) bf16_t As[128 * 32];
    __shared__ __attribute__((aligned(16))) bf16_t Bs[128 * 32];

    int tid = threadIdx.x;
    int m0 = blockIdx.y * 128;
    int n0 = blockIdx.x * 128;

    f32x4 acc[4][4] = {};

    int lane = tid & 63;
    int wv = tid >> 6;
    int wm = (wv >> 1) * 64, wn = (wv & 1) * 64;
    int lm = lane & 15, lq = lane >> 4;

    int srow = tid >> 2;            // 0..63
    int scol = (tid & 3) * 8;       // element col 0/8/16/24
    const bf16_t* Xp0 = X + (size_t)(m0 + srow) * K + scol;
    const bf16_t* Xp1 = X + (size_t)(m0 + 64 + srow) * K + scol;
    int wr0 = n0 + srow;      if (wr0 > N - 1) wr0 = N - 1;  // clamp OOB rows (N=8224 edge)
    int wr1 = n0 + 64 + srow; if (wr1 > N - 1) wr1 = N - 1;
    const bf16_t* Wp0 = W + (size_t)wr0 * K + scol;
    const bf16_t* Wp1 = W + (size_t)wr1 * K + scol;
    bf16_t* lA0 = &As[tid * 8];
    bf16_t* lA1 = &As[2048 + tid * 8];
    bf16_t* lB0 = &Bs[tid * 8];
    bf16_t* lB1 = &Bs[2048 + tid * 8];

    for (int k0 = 0; k0 < K; k0 += 32) {
        __syncthreads();                 // prev iter's LDS reads done
        gld_lds16(Xp0 + k0, lA0);
        gld_lds16(Xp1 + k0, lA1);
        gld_lds16(Wp0 + k0, lB0);
        gld_lds16(Wp1 + k0, lB1);
        __syncthreads();                 // compiler drains vmcnt before barrier

        bf16x8 a[4], b[4];
#pragma unroll
        for (int i = 0; i < 4; ++i)
            a[i] = *(const bf16x8*)&As[(wm + i * 16 + lm) * 32 + lq * 8];
#pragma unroll
        for (int i = 0; i < 4; ++i)
            b[i] = *(const bf16x8*)&Bs[(wn + i * 16 + lm) * 32 + lq * 8];
#pragma unroll
        for (int mi = 0; mi < 4; ++mi)
#pragma unroll
            for (int ni = 0; ni < 4; ++ni)
                acc[mi][ni] = __builtin_amdgcn_mfma_f32_16x16x32_bf16(
                    a[mi], b[ni], acc[mi][ni], 0, 0, 0);
    }

    // epilogue: C/D layout col=lane&15, row=(lane>>4)*4+reg  [verified m89/m91]
#pragma unroll
    for (int mi = 0; mi < 4; ++mi)
#pragma unroll
        for (int ni = 0; ni < 4; ++ni) {
            int n = n0 + wn + ni * 16 + lm;
            if (n >= N) continue;
            int mbase = m0 + wm + mi * 16 + lq * 4;
#pragma unroll
            for (int r = 0; r < 4; ++r) {
                size_t off = (size_t)(mbase + r) * N + n;
                float v = acc[mi][ni][r];
                if (RES) v += R[off];
                O[off] = (OT)v;
            }
        }
}

// ---------------------------------------------------------------------------
// causal depthwise conv1d (taps=4): rolling registers per channel.
// zx = zxbcdt bf16 [NTOK, 8224]; xBC at cols 2048..8191. out bf16 [NTOK, 6144].
__global__ __launch_bounds__(256) void conv_kernel(
    const bf16_t* __restrict__ zx, const float* __restrict__ cw,
    const float* __restrict__ cb, bf16_t* __restrict__ out)
{
    int c = blockIdx.x * 256 + threadIdx.x;   // 0..6143
    int l0 = blockIdx.y * 128;
    int b = blockIdx.z;
    float w0 = cw[c * 4 + 0], w1 = cw[c * 4 + 1];
    float w2 = cw[c * 4 + 2], w3 = cw[c * 4 + 3];
    float bias = cb[c];
    const bf16_t* src = zx + (size_t)b * L_SEQ * D_IN_PROJ + 2048 + c;
    bf16_t* dst = out + (size_t)b * L_SEQ * CONV_DIM + c;
    float xm3 = (l0 >= 3) ? (float)src[(size_t)(l0 - 3) * D_IN_PROJ] : 0.f;
    float xm2 = (l0 >= 2) ? (float)src[(size_t)(l0 - 2) * D_IN_PROJ] : 0.f;
    float xm1 = (l0 >= 1) ? (float)src[(size_t)(l0 - 1) * D_IN_PROJ] : 0.f;
    for (int l = l0; l < l0 + 128; ++l) {
        float xc = (float)src[(size_t)l * D_IN_PROJ];
        float r = bias + xm3 * w0 + xm2 * w1 + xm1 * w2 + xc * w3;
        dst[(size_t)l * CONV_DIM] = (bf16_t)r;
        xm3 = xm2; xm2 = xm1; xm1 = xc;
    }
}

// ---------------------------------------------------------------------------
// SSM scan, 1 block per (b,h). state[p][n] (64x64) as 2p x 8n per thread.
// a = exp(-softplus(A_log)) = 1/(1+e^v). Stages 16 timesteps into LDS per
// barrier pair. Fuses y += D*x and gated = y*silu(z+zb); writes bf16.
__global__ __launch_bounds__(256) void scan_kernel(
    const bf16_t* __restrict__ conv, const bf16_t* __restrict__ zx,
    const float* __restrict__ Dp, const float* __restrict__ zb,
    bf16_t* __restrict__ gated)
{
    const int S = 16;
    __shared__ __attribute__((aligned(16))) float xs[S][64];
    __shared__ __attribute__((aligned(16))) float bs[S][64];
    __shared__ __attribute__((aligned(16))) float cs[S][64];
    __shared__ __attribute__((aligned(16))) float zs[S][64];
    __shared__ float as_[S];

    int bh = blockIdx.x;
    int b = bh >> 5, h = bh & 31;
    int tid = threadIdx.x;
    int lane = tid & 63, wv = tid >> 6;
    int pt = tid >> 3, nt = tid & 7;
    int p0 = pt * 2, n0 = nt * 8;

    float st0[8] = {0, 0, 0, 0, 0, 0, 0, 0};
    float st1[8] = {0, 0, 0, 0, 0, 0, 0, 0};

    float Dh  = Dp[h];
    float zb0 = zb[h * 64 + p0];
    float zb1 = zb[h * 64 + p0 + 1];

    const bf16_t* cbase = conv + (size_t)b * L_SEQ * CONV_DIM + h * 64;
    const bf16_t* zbase = zx + (size_t)b * L_SEQ * D_IN_PROJ + h * 64;
    const bf16_t* abase = zx + (size_t)b * L_SEQ * D_IN_PROJ + 8192 + h;
    bf16_t* obase = gated + (size_t)b * L_SEQ * D_INNER + h * 64;

    for (int t0 = 0; t0 < L_SEQ; t0 += S) {
        for (int s = 0; s < S; ++s) {
            size_t row = (size_t)(t0 + s);
            if (wv == 0)      xs[s][lane] = (float)cbase[row * CONV_DIM + lane];
            else if (wv == 1) bs[s][lane] = (float)cbase[row * CONV_DIM + 2048 + lane];
            else if (wv == 2) cs[s][lane] = (float)cbase[row * CONV_DIM + 4096 + lane];
            else              zs[s][lane] = (float)zbase[row * D_IN_PROJ + lane];
        }
        if (tid < S) {
            float v = (float)abase[(size_t)(t0 + tid) * D_IN_PROJ];
            as_[tid] = 1.f / (1.f + __expf(v));     // exp(-softplus(v))
        }
        __syncthreads();

        for (int s = 0; s < S; ++s) {
            float a = as_[s];
            float x0 = xs[s][p0], x1 = xs[s][p0 + 1];
            float part0 = 0.f, part1 = 0.f;
#pragma unroll
            for (int j = 0; j < 8; ++j) {
                float Bv = bs[s][n0 + j];
                float Cv = cs[s][n0 + j];
                st0[j] = a * st0[j] + x0 * Bv;
                st1[j] = a * st1[j] + x1 * Bv;
                part0 += st0[j] * Cv;
                part1 += st1[j] * Cv;
            }
            for (int o = 1; o < 8; o <<= 1) {
                part0 += __shfl_xor(part0, o, 64);
                part1 += __shfl_xor(part1, o, 64);
            }
            if (nt == 0) {
                float y0 = part0 + Dh * x0;
                float y1 = part1 + Dh * x1;
                float z0 = zs[s][p0] + zb0;
                float z1 = zs[s][p0 + 1] + zb1;
                y0 *= z0 / (1.f + __expf(-z0));
                y1 *= z1 / (1.f + __expf(-z1));
                bf16_t* o2 = obase + (size_t)(t0 + s) * D_INNER + p0;
                o2[0] = (bf16_t)y0;
                o2[1] = (bf16_t)y1;
            }
        }
        __syncthreads();
    }
}

// ---------------------------------------------------------------------------
// act = bf16(silu(g) * u), 8 elems/thread; safe in-place over g.
__global__ __launch_bounds__(256) void act_kernel(
    const bf16x8* __restrict__ g, const bf16x8* __restrict__ u,
    bf16x8* __restrict__ act, int n8)
{
    int i = blockIdx.x * 256 + threadIdx.x;
    if (i >= n8) return;
    bf16x8 gv = g[i], uv = u[i], r;
#pragma unroll
    for (int j = 0; j < 8; ++j) {
        float x = (float)gv[j];
        r[j] = (bf16_t)((x / (1.f + __expf(-x))) * (float)uv[j]);
    }
    act[i] = r;
}

// ---------------------------------------------------------------------------
extern "C" void kernel_launch(void* const* d_in, const int* in_sizes, int n_in,
                              void* d_out, int out_size, void* d_ws, size_t ws_size,
                              hipStream_t stream) {
    const float* hidden     = (const float*)d_in[0];
    const float* mask       = (const float*)d_in[1];
    const float* in_proj_w  = (const float*)d_in[2];
    const float* conv_w     = (const float*)d_in[3];
    const float* conv_b     = (const float*)d_in[4];
    const float* z_bias     = (const float*)d_in[5];
    const float* Dvec       = (const float*)d_in[6];
    const float* out_proj_w = (const float*)d_in[7];
    const float* ln1_w      = (const float*)d_in[8];
    const float* ln2_w      = (const float*)d_in[9];
    const float* gate_w     = (const float*)d_in[10];
    const float* up_w       = (const float*)d_in[11];
    const float* down_w     = (const float*)d_in[12];
    float* out = (float*)d_out;          // [4096, 2048] f32; also holds h2 from step 5 on

    // workspace arena (184,942,592 B total):
    //   [0, 67371008)          zxb bf16 [4096,8224]     (steps 2-4)
    //                          gbuf@0, ubuf@45088768    (steps 7-9; zxb/convo dead)
    //   [67371008, 117702656)  convo bf16 [4096,6144]   (steps 3-4)
    //   [117702656, 134479872) hn (steps 1-2) / gated (steps 4-5) bf16 [4096,2048]
    //   [134479872, 151257088) h2n bf16 [4096,2048]     (steps 6-8)
    //   [151257088, 184942592) wbuf bf16 (33,685,504 B) lazily-converted weights
    char* ws = (char*)d_ws;
    bf16_t* zxb   = (bf16_t*)(ws + 0);
    bf16_t* convo = (bf16_t*)(ws + 67371008);
    bf16_t* hn    = (bf16_t*)(ws + 117702656);
    bf16_t* gated = (bf16_t*)(ws + 117702656);
    bf16_t* h2n   = (bf16_t*)(ws + 134479872);
    bf16_t* wbuf  = (bf16_t*)(ws + 151257088);
    bf16_t* gbuf  = (bf16_t*)(ws + 0);
    bf16_t* ubuf  = (bf16_t*)(ws + 45088768);

    // 1. hn = rmsnorm(hidden, ln1) * mask        (bf16)
    rmsnorm_kernel<<<NTOK, 256, 0, stream>>>(hidden, ln1_w, mask, hn);
    // 2. zxb = hn @ in_proj^T  [4096, 8224]
    cvt_kernel<<<8224, 256, 0, stream>>>(in_proj_w, wbuf, D_IN_PROJ * D_MODEL / 8);
    gemm_bt<false, bf16_t><<<dim3(65, 32), 256, 0, stream>>>(hn, wbuf, nullptr, zxb, D_IN_PROJ, D_MODEL);
    // 3. causal depthwise conv on xBC cols
    conv_kernel<<<dim3(24, 16, 2), 256, 0, stream>>>(zxb, conv_w, conv_b, convo);
    // 4. SSM scan + D*x + silu(z)-gating -> gated bf16 [4096, 2048]
    scan_kernel<<<64, 256, 0, stream>>>(convo, zxb, Dvec, z_bias, gated);
    // 5. h2 = gated @ out_proj^T + hidden        (f32, stored in d_out)
    cvt_kernel<<<2048, 256, 0, stream>>>(out_proj_w, wbuf, D_MODEL * D_INNER / 8);
    gemm_bt<true, float><<<dim3(16, 32), 256, 0, stream>>>(gated, wbuf, hidden, out, D_MODEL, D_INNER);
    // 6. h2n = rmsnorm(h2, ln2)                  (bf16)
    rmsnorm_kernel<<<NTOK, 256, 0, stream>>>(out, ln2_w, nullptr, h2n);
    // 7. g = h2n @ gate_w^T   [4096, 5504]
    cvt_kernel<<<5504, 256, 0, stream>>>(gate_w, wbuf, INTER * D_MODEL / 8);
    gemm_bt<false, bf16_t><<<dim3(43, 32), 256, 0, stream>>>(h2n, wbuf, nullptr, gbuf, INTER, D_MODEL);
    // 8. u = h2n @ up_w^T ; act = silu(g)*u (in-place over gbuf)
    cvt_kernel<<<5504, 256, 0, stream>>>(up_w, wbuf, INTER * D_MODEL / 8);
    gemm_bt<false, bf16_t><<<dim3(43, 32), 256, 0, stream>>>(h2n, wbuf, nullptr, ubuf, INTER, D_MODEL);
    act_kernel<<<11008, 256, 0, stream>>>(
        (const bf16x8*)gbuf, (const bf16x8*)ubuf, (bf16x8*)gbuf, NTOK * INTER / 8);
    // 9. out = act @ down_w^T + h2               (f32, in-place residual over d_out)
    cvt_kernel<<<5504, 256, 0, stream>>>(down_w, wbuf, D_MODEL * INTER / 8);
    gemm_bt<true, float><<<dim3(16, 32), 256, 0, stream>>>(gbuf, wbuf, out, out, D_MODEL, INTER);
}

// Round 3
// 1149.786 us; speedup vs baseline: 2.2785x; 2.2785x over previous
//
#include <hip/hip_runtime.h>
#include <math.h>

typedef __bf16 bf16_t;
typedef __attribute__((ext_vector_type(8))) __bf16 bf16x8;
typedef __attribute__((ext_vector_type(4))) float f32x4;

#define D_MODEL   2048
#define L_SEQ     2048
#define BATCH     2
#define NTOK      4096      // BATCH * L_SEQ
#define N_HEADS   32
#define D_STATE   64
#define HEADDIM   64
#define D_INNER   2048
#define CONV_DIM  6144      // d_inner + 2*H*N
#define D_IN_PROJ 8224      // 2*d_inner + 2*H*N + H
#define INTER     5504
#define QCHUNK    128       // scan chunk length
#define KCHUNKS   16        // L_SEQ / QCHUNK

// ---------------------------------------------------------------------------
// async global->LDS (width 16B). HW dest = wave-uniform base + lane*16; our
// LDS layout is flat tid*16 so per-lane pointers match HW placement exactly.
__device__ __forceinline__ void gld_lds16(const void* g, void* l) {
    __builtin_amdgcn_global_load_lds(
        (const __attribute__((address_space(1))) unsigned int*)g,
        (__attribute__((address_space(3))) unsigned int*)l, 16, 0, 0);
}

// ---------------------------------------------------------------------------
// f32 -> bf16 convert, 8 elems/thread
__global__ __launch_bounds__(256) void cvt_kernel(
    const float* __restrict__ s, bf16_t* __restrict__ d, int n8)
{
    int i = blockIdx.x * 256 + threadIdx.x;
    if (i >= n8) return;
    const float4* s4 = (const float4*)s;
    float4 a = s4[2 * i], b = s4[2 * i + 1];
    bf16x8 r;
    r[0] = (bf16_t)a.x; r[1] = (bf16_t)a.y; r[2] = (bf16_t)a.z; r[3] = (bf16_t)a.w;
    r[4] = (bf16_t)b.x; r[5] = (bf16_t)b.y; r[6] = (bf16_t)b.z; r[7] = (bf16_t)b.w;
    ((bf16x8*)d)[i] = r;
}

// ---------------------------------------------------------------------------
// RMSNorm: one block per token row; f32 in, bf16 out.
__global__ __launch_bounds__(256) void rmsnorm_kernel(
    const float* __restrict__ x, const float* __restrict__ w,
    const float* __restrict__ mask, bf16_t* __restrict__ out)
{
    __shared__ float red[4];
    __shared__ float sinv;
    int row = blockIdx.x;
    const float* xr = x + (size_t)row * D_MODEL;
    float xv[8];
    float ss = 0.f;
#pragma unroll
    for (int i = 0; i < 8; ++i) {
        float v = xr[threadIdx.x + 256 * i];
        xv[i] = v;
        ss += v * v;
    }
    for (int off = 32; off >= 1; off >>= 1) ss += __shfl_down(ss, off, 64);
    int lane = threadIdx.x & 63, wv = threadIdx.x >> 6;
    if (lane == 0) red[wv] = ss;
    __syncthreads();
    if (threadIdx.x == 0) {
        float t = red[0] + red[1] + red[2] + red[3];
        sinv = rsqrtf(t / (float)D_MODEL + 1e-6f);
    }
    __syncthreads();
    float s = sinv;
    float m = mask ? mask[row] : 1.f;
    bf16_t* orow = out + (size_t)row * D_MODEL;
#pragma unroll
    for (int i = 0; i < 8; ++i) {
        int c = threadIdx.x + 256 * i;
        orow[c] = (bf16_t)(xv[i] * s * w[c] * m);
    }
}

// ---------------------------------------------------------------------------
// GEMM: O[M,N] = X[M,K] @ W[N,K]^T (+ optional f32 residual R), bf16 inputs,
// fp32 accum, OT output. 128x128 tile, BK=32, 4 waves 2x2, m97 structure.
template <bool RES, typename OT>
__global__ __launch_bounds__(256) void gemm_bt(
    const bf16_t* __restrict__ X, const bf16_t* __restrict__ W,
    const float* __restrict__ R, OT* __restrict__ O,
    int N, int K)
{
    __shared__ __attribute__((aligned(16))) bf16_t As[128 * 32];
    __shared__ __attribute__((aligned(16))) bf16_t Bs[128 * 32];

    int tid = threadIdx.x;
    int m0 = blockIdx.y * 128;
    int n0 = blockIdx.x * 128;

    f32x4 acc[4][4] = {};

    int lane = tid & 63;
    int wv = tid >> 6;
    int wm = (wv >> 1) * 64, wn = (wv & 1) * 64;
    int lm = lane & 15, lq = lane >> 4;

    int srow = tid >> 2;            // 0..63
    int scol = (tid & 3) * 8;       // element col 0/8/16/24
    const bf16_t* Xp0 = X + (size_t)(m0 + srow) * K + scol;
    const bf16_t* Xp1 = X + (size_t)(m0 + 64 + srow) * K + scol;
    int wr0 = n0 + srow;      if (wr0 > N - 1) wr0 = N - 1;  // clamp OOB rows (N=8224 edge)
    int wr1 = n0 + 64 + srow; if (wr1 > N - 1) wr1 = N - 1;
    const bf16_t* Wp0 = W + (size_t)wr0 * K + scol;
    const bf16_t* Wp1 = W + (size_t)wr1 * K + scol;
    bf16_t* lA0 = &As[tid * 8];
    bf16_t* lA1 = &As[2048 + tid * 8];
    bf16_t* lB0 = &Bs[tid * 8];
    bf16_t* lB1 = &Bs[2048 + tid * 8];

    for (int k0 = 0; k0 < K; k0 += 32) {
        __syncthreads();                 // prev iter's LDS reads done
        gld_lds16(Xp0 + k0, lA0);
        gld_lds16(Xp1 + k0, lA1);
        gld_lds16(Wp0 + k0, lB0);
        gld_lds16(Wp1 + k0, lB1);
        __syncthreads();                 // compiler drains vmcnt before barrier

        bf16x8 a[4], b[4];
#pragma unroll
        for (int i = 0; i < 4; ++i)
            a[i] = *(const bf16x8*)&As[(wm + i * 16 + lm) * 32 + lq * 8];
#pragma unroll
        for (int i = 0; i < 4; ++i)
            b[i] = *(const bf16x8*)&Bs[(wn + i * 16 + lm) * 32 + lq * 8];
#pragma unroll
        for (int mi = 0; mi < 4; ++mi)
#pragma unroll
            for (int ni = 0; ni < 4; ++ni)
                acc[mi][ni] = __builtin_amdgcn_mfma_f32_16x16x32_bf16(
                    a[mi], b[ni], acc[mi][ni], 0, 0, 0);
    }

    // epilogue: C/D layout col=lane&15, row=(lane>>4)*4+reg  [verified m89/m91]
#pragma unroll
    for (int mi = 0; mi < 4; ++mi)
#pragma unroll
        for (int ni = 0; ni < 4; ++ni) {
            int n = n0 + wn + ni * 16 + lm;
            if (n >= N) continue;
            int mbase = m0 + wm + mi * 16 + lq * 4;
#pragma unroll
            for (int r = 0; r < 4; ++r) {
                size_t off = (size_t)(mbase + r) * N + n;
                float v = acc[mi][ni][r];
                if (RES) v += R[off];
                O[off] = (OT)v;
            }
        }
}

// ---------------------------------------------------------------------------
// causal depthwise conv1d (taps=4): rolling registers per channel.
__global__ __launch_bounds__(256) void conv_kernel(
    const bf16_t* __restrict__ zx, const float* __restrict__ cw,
    const float* __restrict__ cb, bf16_t* __restrict__ out)
{
    int c = blockIdx.x * 256 + threadIdx.x;   // 0..6143
    int l0 = blockIdx.y * 128;
    int b = blockIdx.z;
    float w0 = cw[c * 4 + 0], w1 = cw[c * 4 + 1];
    float w2 = cw[c * 4 + 2], w3 = cw[c * 4 + 3];
    float bias = cb[c];
    const bf16_t* src = zx + (size_t)b * L_SEQ * D_IN_PROJ + 2048 + c;
    bf16_t* dst = out + (size_t)b * L_SEQ * CONV_DIM + c;
    float xm3 = (l0 >= 3) ? (float)src[(size_t)(l0 - 3) * D_IN_PROJ] : 0.f;
    float xm2 = (l0 >= 2) ? (float)src[(size_t)(l0 - 2) * D_IN_PROJ] : 0.f;
    float xm1 = (l0 >= 1) ? (float)src[(size_t)(l0 - 1) * D_IN_PROJ] : 0.f;
    for (int l = l0; l < l0 + 128; ++l) {
        float xc = (float)src[(size_t)l * D_IN_PROJ];
        float r = bias + xm3 * w0 + xm2 * w1 + xm1 * w2 + xc * w3;
        dst[(size_t)l * CONV_DIM] = (bf16_t)r;
        xm3 = xm2; xm2 = xm1; xm1 = xc;
    }
}

// ---------------------------------------------------------------------------
// SSM scan pass A: per-(b,h,chunk) state-only scan over Q=128 steps.
// Computes S_end[p][n] = sum_t (prod_{i>t} a_i) x_t[p] B_t[n] and
// aprod = prod a_i. No C-reduction, no shuffles. grid (K,H,B).
__global__ __launch_bounds__(256) void scan_state_kernel(
    const bf16_t* __restrict__ conv, const bf16_t* __restrict__ zx,
    float* __restrict__ Schunk, float* __restrict__ Aprod)
{
    const int SS = 32;
    __shared__ __attribute__((aligned(16))) float xs[SS][64];
    __shared__ __attribute__((aligned(16))) float bs[SS][64];
    __shared__ float as_[SS];

    int k = blockIdx.x, h = blockIdx.y, b = blockIdx.z;
    int tid = threadIdx.x, lane = tid & 63, wv = tid >> 6;
    int pt = tid >> 3, nt = tid & 7;
    int p0 = pt * 2, n0 = nt * 8;

    float st0[8] = {0, 0, 0, 0, 0, 0, 0, 0};
    float st1[8] = {0, 0, 0, 0, 0, 0, 0, 0};
    float aprod = 1.f;

    const bf16_t* cbase = conv + (size_t)b * L_SEQ * CONV_DIM + h * 64;
    const bf16_t* abase = zx + (size_t)b * L_SEQ * D_IN_PROJ + 8192 + h;

    int tstart = k * QCHUNK;
    for (int t0 = tstart; t0 < tstart + QCHUNK; t0 += SS) {
        int soff = (wv >> 1) * 16;     // waves 0,1 -> steps 0..15; 2,3 -> 16..31
        for (int s = 0; s < 16; ++s) {
            size_t row = (size_t)(t0 + soff + s);
            if ((wv & 1) == 0) xs[soff + s][lane] = (float)cbase[row * CONV_DIM + lane];
            else               bs[soff + s][lane] = (float)cbase[row * CONV_DIM + 2048 + lane];
        }
        if (tid < SS) {
            float v = (float)abase[(size_t)(t0 + tid) * D_IN_PROJ];
            as_[tid] = 1.f / (1.f + __expf(v));     // exp(-softplus(v))
        }
        __syncthreads();
        for (int s = 0; s < SS; ++s) {
            float a = as_[s];
            float x0 = xs[s][p0], x1 = xs[s][p0 + 1];
            aprod *= a;
#pragma unroll
            for (int j = 0; j < 8; ++j) {
                float Bv = bs[s][n0 + j];
                st0[j] = a * st0[j] + x0 * Bv;
                st1[j] = a * st1[j] + x1 * Bv;
            }
        }
        __syncthreads();
    }
    size_t base = (((size_t)(b * N_HEADS + h)) * KCHUNKS + k) * 4096;
    float4* d0 = (float4*)&Schunk[base + p0 * 64 + n0];
    d0[0] = make_float4(st0[0], st0[1], st0[2], st0[3]);
    d0[1] = make_float4(st0[4], st0[5], st0[6], st0[7]);
    float4* d1 = (float4*)&Schunk[base + (p0 + 1) * 64 + n0];
    d1[0] = make_float4(st1[0], st1[1], st1[2], st1[3]);
    d1[1] = make_float4(st1[4], st1[5], st1[6], st1[7]);
    if (tid == 0) Aprod[(b * N_HEADS + h) * KCHUNKS + k] = aprod;
}

// ---------------------------------------------------------------------------
// SSM scan pass B: elementwise inter-chunk combine.
// Sinit[k] = aprod[k-1]*Sinit[k-1] + Schunk[k-1], Sinit[0]=0.
// grid 1024: block = bh*16 + slice, thread owns 1 state element.
__global__ __launch_bounds__(256) void scan_combine_kernel(
    const float* __restrict__ Schunk, const float* __restrict__ Aprod,
    float* __restrict__ Sinit)
{
    int bh = blockIdx.x >> 4;
    int e = (blockIdx.x & 15) * 256 + threadIdx.x;   // 0..4095
    size_t base = (size_t)bh * KCHUNKS * 4096 + e;
    float S = 0.f;
    for (int k = 0; k < KCHUNKS; ++k) {
        Sinit[base + (size_t)k * 4096] = S;
        float ap = Aprod[bh * KCHUNKS + k];
        S = ap * S + Schunk[base + (size_t)k * 4096];
    }
}

// ---------------------------------------------------------------------------
// SSM scan pass C: per-(b,h,chunk) output scan from Sinit. Fuses y += D*x and
// gated = y*silu(z+zb); writes bf16 [NTOK, 2048]. grid (K,H,B).
__global__ __launch_bounds__(256) void scan_out_kernel(
    const bf16_t* __restrict__ conv, const bf16_t* __restrict__ zx,
    const float* __restrict__ Sinit, const float* __restrict__ Dp,
    const float* __restrict__ zb, bf16_t* __restrict__ gated)
{
    const int S = 16;
    __shared__ __attribute__((aligned(16))) float xs[S][64];
    __shared__ __attribute__((aligned(16))) float bs[S][64];
    __shared__ __attribute__((aligned(16))) float cs[S][64];
    __shared__ __attribute__((aligned(16))) float zs[S][64];
    __shared__ float as_[S];

    int k = blockIdx.x, h = blockIdx.y, b = blockIdx.z;
    int tid = threadIdx.x;
    int lane = tid & 63, wv = tid >> 6;
    int pt = tid >> 3, nt = tid & 7;
    int p0 = pt * 2, n0 = nt * 8;

    size_t sbase = (((size_t)(b * N_HEADS + h)) * KCHUNKS + k) * 4096;
    float4 v00 = *(const float4*)&Sinit[sbase + p0 * 64 + n0];
    float4 v01 = *(const float4*)&Sinit[sbase + p0 * 64 + n0 + 4];
    float4 v10 = *(const float4*)&Sinit[sbase + (p0 + 1) * 64 + n0];
    float4 v11 = *(const float4*)&Sinit[sbase + (p0 + 1) * 64 + n0 + 4];
    float st0[8] = {v00.x, v00.y, v00.z, v00.w, v01.x, v01.y, v01.z, v01.w};
    float st1[8] = {v10.x, v10.y, v10.z, v10.w, v11.x, v11.y, v11.z, v11.w};

    float Dh  = Dp[h];
    float zb0 = zb[h * 64 + p0];
    float zb1 = zb[h * 64 + p0 + 1];

    const bf16_t* cbase = conv + (size_t)b * L_SEQ * CONV_DIM + h * 64;
    const bf16_t* zbase = zx + (size_t)b * L_SEQ * D_IN_PROJ + h * 64;
    const bf16_t* abase = zx + (size_t)b * L_SEQ * D_IN_PROJ + 8192 + h;
    bf16_t* obase = gated + (size_t)b * L_SEQ * D_INNER + h * 64;

    int tstart = k * QCHUNK;
    for (int t0 = tstart; t0 < tstart + QCHUNK; t0 += S) {
        for (int s = 0; s < S; ++s) {
            size_t row = (size_t)(t0 + s);
            if (wv == 0)      xs[s][lane] = (float)cbase[row * CONV_DIM + lane];
            else if (wv == 1) bs[s][lane] = (float)cbase[row * CONV_DIM + 2048 + lane];
            else if (wv == 2) cs[s][lane] = (float)cbase[row * CONV_DIM + 4096 + lane];
            else              zs[s][lane] = (float)zbase[row * D_IN_PROJ + lane];
        }
        if (tid < S) {
            float v = (float)abase[(size_t)(t0 + tid) * D_IN_PROJ];
            as_[tid] = 1.f / (1.f + __expf(v));     // exp(-softplus(v))
        }
        __syncthreads();

        for (int s = 0; s < S; ++s) {
            float a = as_[s];
            float x0 = xs[s][p0], x1 = xs[s][p0 + 1];
            float part0 = 0.f, part1 = 0.f;
#pragma unroll
            for (int j = 0; j < 8; ++j) {
                float Bv = bs[s][n0 + j];
                float Cv = cs[s][n0 + j];
                st0[j] = a * st0[j] + x0 * Bv;
                st1[j] = a * st1[j] + x1 * Bv;
                part0 += st0[j] * Cv;
                part1 += st1[j] * Cv;
            }
            for (int o = 1; o < 8; o <<= 1) {
                part0 += __shfl_xor(part0, o, 64);
                part1 += __shfl_xor(part1, o, 64);
            }
            if (nt == 0) {
                float y0 = part0 + Dh * x0;
                float y1 = part1 + Dh * x1;
                float z0 = zs[s][p0] + zb0;
                float z1 = zs[s][p0 + 1] + zb1;
                y0 *= z0 / (1.f + __expf(-z0));
                y1 *= z1 / (1.f + __expf(-z1));
                bf16_t* o2 = obase + (size_t)(t0 + s) * D_INNER + p0;
                o2[0] = (bf16_t)y0;
                o2[1] = (bf16_t)y1;
            }
        }
        __syncthreads();
    }
}

// ---------------------------------------------------------------------------
// act = bf16(silu(g) * u), 8 elems/thread; safe in-place over g.
__global__ __launch_bounds__(256) void act_kernel(
    const bf16x8* __restrict__ g, const bf16x8* __restrict__ u,
    bf16x8* __restrict__ act, int n8)
{
    int i = blockIdx.x * 256 + threadIdx.x;
    if (i >= n8) return;
    bf16x8 gv = g[i], uv = u[i], r;
#pragma unroll
    for (int j = 0; j < 8; ++j) {
        float x = (float)gv[j];
        r[j] = (bf16_t)((x / (1.f + __expf(-x))) * (float)uv[j]);
    }
    act[i] = r;
}

// ---------------------------------------------------------------------------
extern "C" void kernel_launch(void* const* d_in, const int* in_sizes, int n_in,
                              void* d_out, int out_size, void* d_ws, size_t ws_size,
                              hipStream_t stream) {
    const float* hidden     = (const float*)d_in[0];
    const float* mask       = (const float*)d_in[1];
    const float* in_proj_w  = (const float*)d_in[2];
    const float* conv_w     = (const float*)d_in[3];
    const float* conv_b     = (const float*)d_in[4];
    const float* z_bias     = (const float*)d_in[5];
    const float* Dvec       = (const float*)d_in[6];
    const float* out_proj_w = (const float*)d_in[7];
    const float* ln1_w      = (const float*)d_in[8];
    const float* ln2_w      = (const float*)d_in[9];
    const float* gate_w     = (const float*)d_in[10];
    const float* up_w       = (const float*)d_in[11];
    const float* down_w     = (const float*)d_in[12];
    float* out = (float*)d_out;          // [4096, 2048] f32; holds h2 from step 5 on

    // workspace arena (184,942,592 B total):
    //   [0, 67371008)          zxb bf16 [4096,8224]   (steps 2-4)
    //                          gbuf@0, ubuf@45088768  (steps 7-9)
    //   [67371008, 117702656)  convo bf16 [4096,6144] (steps 3-4)
    //   [117702656, 134479872) hn (1-2) / gated (4-5) bf16 [4096,2048]
    //   [134479872, 151257088) h2n bf16 (steps 6-8) / Schunk f32 16MB (scan)
    //   [151257088, 184942592) wbuf bf16 33.7MB (gemm weight staging)
    //                          / Sinit f32 16MB + Aprod 4KB (scan)
    char* ws = (char*)d_ws;
    bf16_t* zxb    = (bf16_t*)(ws + 0);
    bf16_t* convo  = (bf16_t*)(ws + 67371008);
    bf16_t* hn     = (bf16_t*)(ws + 117702656);
    bf16_t* gated  = (bf16_t*)(ws + 117702656);
    bf16_t* h2n    = (bf16_t*)(ws + 134479872);
    float*  Schunk = (float*) (ws + 134479872);   // scan-only, aliases h2n
    bf16_t* wbuf   = (bf16_t*)(ws + 151257088);
    float*  Sinit  = (float*) (ws + 151257088);   // scan-only, aliases wbuf
    float*  Aprod  = (float*) (ws + 168034304);
    bf16_t* gbuf   = (bf16_t*)(ws + 0);
    bf16_t* ubuf   = (bf16_t*)(ws + 45088768);

    // 1. hn = rmsnorm(hidden, ln1) * mask        (bf16)
    rmsnorm_kernel<<<NTOK, 256, 0, stream>>>(hidden, ln1_w, mask, hn);
    // 2. zxb = hn @ in_proj^T  [4096, 8224]
    cvt_kernel<<<8224, 256, 0, stream>>>(in_proj_w, wbuf, D_IN_PROJ * D_MODEL / 8);
    gemm_bt<false, bf16_t><<<dim3(65, 32), 256, 0, stream>>>(hn, wbuf, nullptr, zxb, D_IN_PROJ, D_MODEL);
    // 3. causal depthwise conv on xBC cols
    conv_kernel<<<dim3(24, 16, 2), 256, 0, stream>>>(zxb, conv_w, conv_b, convo);
    // 4. chunk-parallel SSM scan (A: chunk states, B: combine, C: outputs)
    scan_state_kernel<<<dim3(KCHUNKS, N_HEADS, BATCH), 256, 0, stream>>>(convo, zxb, Schunk, Aprod);
    scan_combine_kernel<<<1024, 256, 0, stream>>>(Schunk, Aprod, Sinit);
    scan_out_kernel<<<dim3(KCHUNKS, N_HEADS, BATCH), 256, 0, stream>>>(convo, zxb, Sinit, Dvec, z_bias, gated);
    // 5. h2 = gated @ out_proj^T + hidden        (f32, stored in d_out)
    cvt_kernel<<<2048, 256, 0, stream>>>(out_proj_w, wbuf, D_MODEL * D_INNER / 8);
    gemm_bt<true, float><<<dim3(16, 32), 256, 0, stream>>>(gated, wbuf, hidden, out, D_MODEL, D_INNER);
    // 6. h2n = rmsnorm(h2, ln2)                  (bf16)
    rmsnorm_kernel<<<NTOK, 256, 0, stream>>>(out, ln2_w, nullptr, h2n);
    // 7. g = h2n @ gate_w^T   [4096, 5504]
    cvt_kernel<<<5504, 256, 0, stream>>>(gate_w, wbuf, INTER * D_MODEL / 8);
    gemm_bt<false, bf16_t><<<dim3(43, 32), 256, 0, stream>>>(h2n, wbuf, nullptr, gbuf, INTER, D_MODEL);
    // 8. u = h2n @ up_w^T ; act = silu(g)*u (in-place over gbuf)
    cvt_kernel<<<5504, 256, 0, stream>>>(up_w, wbuf, INTER * D_MODEL / 8);
    gemm_bt<false, bf16_t><<<dim3(43, 32), 256, 0, stream>>>(h2n, wbuf, nullptr, ubuf, INTER, D_MODEL);
    act_kernel<<<11008, 256, 0, stream>>>(
        (const bf16x8*)gbuf, (const bf16x8*)ubuf, (bf16x8*)gbuf, NTOK * INTER / 8);
    // 9. out = act @ down_w^T + h2               (f32, in-place residual over d_out)
    cvt_kernel<<<5504, 256, 0, stream>>>(down_w, wbuf, D_MODEL * INTER / 8);
    gemm_bt<true, float><<<dim3(16, 32), 256, 0, stream>>>(gbuf, wbuf, out, out, D_MODEL, INTER);
}